// Round 9
// baseline (2026.825 us; speedup 1.0000x reference)
//
#include <hip/hip_runtime.h>

#define N_USERS 50000
#define N_ENT   150000
#define N_NODES 200000
#define NE      2000000
#define BATCH   8192
#define NB 782          // ceil(N_NODES / 256)

__device__ __forceinline__ float bf2f(unsigned short b) {
    return __uint_as_float(((unsigned int)b) << 16);
}
__device__ __forceinline__ unsigned short f2bf(float f) {
    unsigned int u = __float_as_uint(f);
    u += 0x7FFF + ((u >> 16) & 1);          // round-to-nearest-even
    return (unsigned short)(u >> 16);
}

// ===========================================================================
// CSR build. After: rs0[r] = exclusive row start (N+1 entries), rscur = fill
// cursors; csr_fill assigns slots and records eslot[e] (edge -> CSR slot).
// ===========================================================================
__global__ __launch_bounds__(256) void hist_csr(const int* __restrict__ rows,
                                                int* __restrict__ hist) {
    int e = blockIdx.x * 256 + threadIdx.x;
    if (e < NE) atomicAdd(&hist[rows[e]], 1);
}

// generic 200k-entry exclusive scan over a slice (3 kernels)
__global__ __launch_bounds__(256) void scan1(const int* __restrict__ src,
                                             int* __restrict__ dst,
                                             int* __restrict__ blk) {
    __shared__ int buf[256];
    int i = blockIdx.x * 256 + threadIdx.x;
    int v = (i < N_NODES) ? src[i] : 0;
    buf[threadIdx.x] = v;
    __syncthreads();
    for (int off = 1; off < 256; off <<= 1) {
        int x = (threadIdx.x >= off) ? buf[threadIdx.x - off] : 0;
        __syncthreads();
        buf[threadIdx.x] += x;
        __syncthreads();
    }
    if (i < N_NODES) dst[i] = buf[threadIdx.x] - v;      // exclusive
    if (threadIdx.x == 255) blk[blockIdx.x] = buf[255];
}

__global__ __launch_bounds__(1024) void scan2(int* __restrict__ blk) {
    __shared__ int buf[1024];
    int t = threadIdx.x;
    int v = (t < NB) ? blk[t] : 0;
    buf[t] = v;
    __syncthreads();
    for (int off = 1; off < 1024; off <<= 1) {
        int x = (t >= off) ? buf[t - off] : 0;
        __syncthreads();
        buf[t] += x;
        __syncthreads();
    }
    if (t < NB) blk[t] = buf[t] - v;
}

__global__ __launch_bounds__(256) void scan3_csr(int* __restrict__ rs0,
                                                 int* __restrict__ rscur,
                                                 const int* __restrict__ blk) {
    int i = blockIdx.x * 256 + threadIdx.x;
    if (i < N_NODES) {
        int v = rs0[i] + blk[blockIdx.x];
        rs0[i] = v;
        rscur[i] = v;
    }
    if (i == 0) rs0[N_NODES] = NE;
}

__global__ __launch_bounds__(256) void csr_fill(const int* __restrict__ rows,
                                                const int* __restrict__ cols,
                                                const float* __restrict__ vals,
                                                int* __restrict__ rscur,
                                                int* __restrict__ ccol,
                                                float* __restrict__ cval,
                                                int* __restrict__ eslot) {
    int e = blockIdx.x * 256 + threadIdx.x;
    if (e >= NE) return;
    int pos = atomicAdd(&rscur[rows[e]], 1);
    ccol[pos] = cols[e];
    cval[pos] = vals[e];
    if (eslot) eslot[e] = pos;
}

// ===========================================================================
// Chunk-major CSC: key = (row>>shift)*N + col. Because CSR is row-major,
// chunk c's CSC region is exactly [rs0[c*R], rs0[(c+1)*R]) — the same global
// index space as its CSR slots.
// ===========================================================================
__global__ __launch_bounds__(256) void khist(const int* __restrict__ rows,
                                             const int* __restrict__ cols,
                                             int* __restrict__ hist, int shift) {
    int e = blockIdx.x * 256 + threadIdx.x;
    if (e < NE) atomicAdd(&hist[(rows[e] >> shift) * N_NODES + cols[e]], 1);
}

__global__ __launch_bounds__(256) void kscan3base(int* __restrict__ arr,
                                                  const int* __restrict__ blk,
                                                  const int* __restrict__ rs0,
                                                  int baserow) {
    int i = blockIdx.x * 256 + threadIdx.x;
    if (i < N_NODES) arr[i] += blk[blockIdx.x] + rs0[baserow];
}

__global__ __launch_bounds__(256) void kfill(const int* __restrict__ rows,
                                             const int* __restrict__ cols,
                                             int* __restrict__ kcur,
                                             int* __restrict__ ccolc,
                                             int* __restrict__ cdst,
                                             const int* __restrict__ eslot,
                                             int shift) {
    int e = blockIdx.x * 256 + threadIdx.x;
    if (e >= NE) return;
    int c = cols[e];
    int pos = atomicAdd(&kcur[(rows[e] >> shift) * N_NODES + c], 1);
    ccolc[pos] = c;
    cdst[pos] = eslot[e];
}

// ---------------------------------------------------------------------------
// t0 = bf16(concat(ue, ee)) — 64-dim row = 128 B = one cache line.
// ---------------------------------------------------------------------------
__global__ __launch_bounds__(256) void build_t0(const float* __restrict__ ue,
                                                const float* __restrict__ ee,
                                                unsigned short* __restrict__ t0) {
    int i = blockIdx.x * 256 + threadIdx.x;
    const int total = N_NODES * 64 / 4;
    if (i >= total) return;
    const int uelems = N_USERS * 64 / 4;
    float4 v = (i < uelems) ? ((const float4*)ue)[i]
                            : ((const float4*)ee)[i - uelems];
    ushort4 o;
    o.x = f2bf(v.x); o.y = f2bf(v.y); o.z = f2bf(v.z); o.w = f2bf(v.w);
    ((ushort4*)t0)[i] = o;
}

// ===========================================================================
// Phase A: permute. Edges in column order -> reads of t are SEQUENTIAL;
// each edge's 128 B bf16 row is written to its CSR slot (random full-line
// write, fire-and-forget). 32 lanes per edge, uint copy.
// ===========================================================================
__global__ __launch_bounds__(256) void permuteA(const int* __restrict__ ccolc,
                                                const int* __restrict__ cdst,
                                                const unsigned short* __restrict__ t,
                                                unsigned short* __restrict__ buf,
                                                const int* __restrict__ rs0,
                                                int row_lo, int row_hi) {
    const int sb = rs0[row_lo];
    const int se = rs0[row_hi];
    int gid = blockIdx.x * 256 + threadIdx.x;
    int p = sb + (gid >> 5);
    int l = gid & 31;
    if (p >= se) return;
    int col = ccolc[p];
    int dst = cdst[p];
    ((unsigned int*)(buf + (size_t)(dst - sb) * 64))[l] =
        ((const unsigned int*)(t + (size_t)col * 64))[l];
}

// ===========================================================================
// Phase B: fused streaming-accumulate + transform (DIN=64). Each row-wave
// reads its CSR-contiguous buf slice (streaming, 4-way ILP) — no random
// reads anywhere. Transform/epilogue identical to the verified r7 kernel.
// ===========================================================================
template <int DOUT, int L0, int WT>
__global__ __launch_bounds__(1024) void permB(
        const int* __restrict__ rs0, const float* __restrict__ cval,
        const unsigned short* __restrict__ buf,
        const float* __restrict__ ue, const float* __restrict__ ee,
        const float* __restrict__ xin,
        const float* __restrict__ Wg, const float* __restrict__ bg,
        const float* __restrict__ Wb, const float* __restrict__ bb,
        float* __restrict__ xout, unsigned short* __restrict__ tout,
        float* __restrict__ norm_out, int row_lo, int row_hi) {
    constexpr int DIN = 64;
    __shared__ float sWg[DIN * DOUT];
    __shared__ float sWb[DIN * DOUT];
    __shared__ float sbg[DOUT];
    __shared__ float sbb[DOUT];
    for (int i = threadIdx.x; i < DIN * DOUT; i += 1024) {
        sWg[i] = Wg[i];
        sWb[i] = Wb[i];
    }
    if (threadIdx.x < DOUT) {
        sbg[threadIdx.x] = bg[threadIdx.x];
        sbb[threadIdx.x] = bb[threadIdx.x];
    }
    __syncthreads();

    const int lane = threadIdx.x & 63;
    const int row  = row_lo + ((blockIdx.x * 1024 + threadIdx.x) >> 6);
    const bool valid = row < row_hi;
    const int sb = rs0[row_lo];

    float acc = 0.f;
    if (valid) {
        int start = rs0[row], end = rs0[row + 1];
        float a0 = 0.f, a1 = 0.f, a2 = 0.f, a3 = 0.f;
        int s = start;
        for (; s + 4 <= end; s += 4) {
            size_t b = (size_t)(s - sb) * 64 + lane;
            float v0 = cval[s], v1 = cval[s + 1], v2 = cval[s + 2], v3 = cval[s + 3];
            a0 = fmaf(v0, bf2f(buf[b]), a0);
            a1 = fmaf(v1, bf2f(buf[b + 64]), a1);
            a2 = fmaf(v2, bf2f(buf[b + 128]), a2);
            a3 = fmaf(v3, bf2f(buf[b + 192]), a3);
        }
        for (; s < end; s++)
            a0 = fmaf(cval[s], bf2f(buf[(size_t)(s - sb) * 64 + lane]), a0);
        acc = (a0 + a1) + (a2 + a3);
    }

    float e = 0.f;
    if (valid) {
        if (L0) {
            e = (row < N_USERS) ? ue[(size_t)row * 64 + lane]
                                : ee[(size_t)(row - N_USERS) * 64 + lane];
        } else {
            e = xin[(size_t)row * 64 + lane];
        }
    }
    float h = e + acc;
    float p = e * acc;

    float ag = (lane < DOUT) ? sbg[lane] : 0.f;
    float ab = (lane < DOUT) ? sbb[lane] : 0.f;
#pragma unroll
    for (int k = 0; k < DIN; k++) {
        float hk = __shfl(h, k);
        float pk = __shfl(p, k);
        if (lane < DOUT) {
            ag = fmaf(hk, sWg[k * DOUT + lane], ag);
            ab = fmaf(pk, sWb[k * DOUT + lane], ab);
        }
    }
    ag = ag > 0.f ? ag : 0.01f * ag;
    ab = ab > 0.f ? ab : 0.01f * ab;
    float nv = (lane < DOUT) ? (ag + ab) : 0.f;

    float ss = nv * nv;
#pragma unroll
    for (int off = 32; off > 0; off >>= 1) ss += __shfl_xor(ss, off);
    float nrm = fmaxf(sqrtf(ss), 1e-12f);

    if (valid && lane < DOUT) {
        xout[(size_t)row * DOUT + lane] = nv;
        if (WT) tout[(size_t)row * DOUT + lane] = f2bf(nv);
    }
    if (valid && lane == 0) norm_out[row] = nrm;
}

// ===========================================================================
// r7 gather-fused kernel (verified): used for layer 2 and as full fallback
// when ws_size can't host the permute buffer.
// ===========================================================================
template <int DIN, int DOUT, int L0, int WT>
__global__ __launch_bounds__(1024) void gatherT(
        const int* __restrict__ rs0,
        const int* __restrict__ ccol, const float* __restrict__ cval,
        const unsigned short* __restrict__ tin,
        const float* __restrict__ ue, const float* __restrict__ ee,
        const float* __restrict__ xin,
        const float* __restrict__ Wg, const float* __restrict__ bg,
        const float* __restrict__ Wb, const float* __restrict__ bb,
        float* __restrict__ xout, unsigned short* __restrict__ tout,
        float* __restrict__ norm_out) {
    __shared__ float sWg[DIN * DOUT];
    __shared__ float sWb[DIN * DOUT];
    __shared__ float sbg[DOUT];
    __shared__ float sbb[DOUT];
    for (int i = threadIdx.x; i < DIN * DOUT; i += 1024) {
        sWg[i] = Wg[i];
        sWb[i] = Wb[i];
    }
    if (threadIdx.x < DOUT) {
        sbg[threadIdx.x] = bg[threadIdx.x];
        sbb[threadIdx.x] = bb[threadIdx.x];
    }
    __syncthreads();

    constexpr int EPG = 64 / DIN;
    const int lane = threadIdx.x & 63;
    const int g    = lane / DIN;
    const int d    = lane % DIN;
    const int row  = (blockIdx.x * 1024 + threadIdx.x) >> 6;

    float acc0 = 0.f, acc1 = 0.f, acc2 = 0.f, acc3 = 0.f;
    const int start = rs0[row];
    const int end   = rs0[row + 1];
    for (int base = start; base < end; base += 64) {
        int n = end - base;
        if (n > 64) n = 64;
        int   mycol = 0;
        float myval = 0.f;
        if (lane < n) {
            mycol = ccol[base + lane];
            myval = cval[base + lane];
        }
        const int np = (n + 4 * EPG - 1) & ~(4 * EPG - 1);
        for (int i = 0; i < np; i += 4 * EPG) {
            int c0 = __shfl(mycol, i + 0 * EPG + g);
            int c1 = __shfl(mycol, i + 1 * EPG + g);
            int c2 = __shfl(mycol, i + 2 * EPG + g);
            int c3 = __shfl(mycol, i + 3 * EPG + g);
            float v0 = __shfl(myval, i + 0 * EPG + g);
            float v1 = __shfl(myval, i + 1 * EPG + g);
            float v2 = __shfl(myval, i + 2 * EPG + g);
            float v3 = __shfl(myval, i + 3 * EPG + g);
            float x0 = bf2f(tin[(size_t)c0 * DIN + d]);
            float x1 = bf2f(tin[(size_t)c1 * DIN + d]);
            float x2 = bf2f(tin[(size_t)c2 * DIN + d]);
            float x3 = bf2f(tin[(size_t)c3 * DIN + d]);
            acc0 = fmaf(v0, x0, acc0);
            acc1 = fmaf(v1, x1, acc1);
            acc2 = fmaf(v2, x2, acc2);
            acc3 = fmaf(v3, x3, acc3);
        }
    }
    float acc = (acc0 + acc1) + (acc2 + acc3);
    if (DIN == 32) acc += __shfl_xor(acc, 32);

    float e = 0.f;
    if (lane < DIN) {
        if (L0) {
            e = (row < N_USERS) ? ue[(size_t)row * 64 + lane]
                                : ee[(size_t)(row - N_USERS) * 64 + lane];
        } else {
            e = xin[(size_t)row * DIN + lane];
        }
    }
    float h = e + acc;
    float p = e * acc;

    float ag = (lane < DOUT) ? sbg[lane] : 0.f;
    float ab = (lane < DOUT) ? sbb[lane] : 0.f;
#pragma unroll
    for (int k = 0; k < DIN; k++) {
        float hk = __shfl(h, k);
        float pk = __shfl(p, k);
        if (lane < DOUT) {
            ag = fmaf(hk, sWg[k * DOUT + lane], ag);
            ab = fmaf(pk, sWb[k * DOUT + lane], ab);
        }
    }
    ag = ag > 0.f ? ag : 0.01f * ag;
    ab = ab > 0.f ? ab : 0.01f * ab;
    float nv = (lane < DOUT) ? (ag + ab) : 0.f;

    float ss = nv * nv;
#pragma unroll
    for (int off = 32; off > 0; off >>= 1) ss += __shfl_xor(ss, off);
    float nrm = fmaxf(sqrtf(ss), 1e-12f);

    if (lane < DOUT) {
        xout[(size_t)row * DOUT + lane] = nv;
        if (WT) tout[(size_t)row * DOUT + lane] = f2bf(nv);
    }
    if (lane == 0) norm_out[row] = nrm;
}

// ===========================================================================
// Scoring: sections 64 raw + 64/n0 + 32/n1 + 16/n2 (norms divided in).
// ===========================================================================
__global__ __launch_bounds__(256) void score_kernel(
        const int* __restrict__ users, const int* __restrict__ pos,
        const int* __restrict__ neg,
        const float* __restrict__ ue, const float* __restrict__ ee,
        const float* __restrict__ e1, const float* __restrict__ n0,
        const float* __restrict__ e2, const float* __restrict__ n1,
        const float* __restrict__ e3, const float* __restrict__ n2,
        float* __restrict__ out) {
    int gid  = blockIdx.x * 256 + threadIdx.x;
    int idx  = gid >> 6;
    int lane = gid & 63;
    if (idx >= BATCH) return;
    int u  = users[idx];
    int pe = pos[idx];
    int ne = neg[idx];
    int pn = N_USERS + pe;
    int nn = N_USERS + ne;

    float s1p = 1.0f / (n0[u] * n0[pn]);
    float s1n = 1.0f / (n0[u] * n0[nn]);
    float s2p = 1.0f / (n1[u] * n1[pn]);
    float s2n = 1.0f / (n1[u] * n1[nn]);
    float s3p = 1.0f / (n2[u] * n2[pn]);
    float s3n = 1.0f / (n2[u] * n2[nn]);

    float ap = 0.f, an = 0.f;
    {
        float xu = ue[(size_t)u * 64 + lane];
        ap += xu * ee[(size_t)pe * 64 + lane];
        an += xu * ee[(size_t)ne * 64 + lane];
    }
    {
        float xu = e1[(size_t)u * 64 + lane];
        ap += xu * e1[(size_t)pn * 64 + lane] * s1p;
        an += xu * e1[(size_t)nn * 64 + lane] * s1n;
    }
    if (lane < 32) {
        float xu = e2[(size_t)u * 32 + lane];
        ap += xu * e2[(size_t)pn * 32 + lane] * s2p;
        an += xu * e2[(size_t)nn * 32 + lane] * s2n;
    } else if (lane < 48) {
        int d = lane - 32;
        float xu = e3[(size_t)u * 16 + d];
        ap += xu * e3[(size_t)pn * 16 + d] * s3p;
        an += xu * e3[(size_t)nn * 16 + d] * s3n;
    }
#pragma unroll
    for (int off = 32; off > 0; off >>= 1) {
        ap += __shfl_xor(ap, off);
        an += __shfl_xor(an, off);
    }
    if (lane == 0) {
        out[2 * idx + 0] = ap;
        out[2 * idx + 1] = an;
    }
}

// ===========================================================================
extern "C" void kernel_launch(void* const* d_in, const int* in_sizes, int n_in,
                              void* d_out, int out_size, void* d_ws, size_t ws_size,
                              hipStream_t stream) {
    const int*   users = (const int*)d_in[0];
    const int*   pos   = (const int*)d_in[1];
    const int*   neg   = (const int*)d_in[2];
    const int*   rows  = (const int*)d_in[3];
    const int*   cols  = (const int*)d_in[4];
    const float* vals  = (const float*)d_in[5];
    const float* ue    = (const float*)d_in[6];
    const float* ee    = (const float*)d_in[7];
    const float* Wg0 = (const float*)d_in[8],  *bg0 = (const float*)d_in[9];
    const float* Wb0 = (const float*)d_in[10], *bb0 = (const float*)d_in[11];
    const float* Wg1 = (const float*)d_in[12], *bg1 = (const float*)d_in[13];
    const float* Wb1 = (const float*)d_in[14], *bb1 = (const float*)d_in[15];
    const float* Wg2 = (const float*)d_in[16], *bg2 = (const float*)d_in[17];
    const float* Wb2 = (const float*)d_in[18], *bb2 = (const float*)d_in[19];

    // ---- fixed workspace (the r7-proven ~174 MB set) ----
    char* basep = (char*)d_ws;
    size_t off = 0;
    auto A = [&](size_t n) { char* q = basep + off; off += (n + 127) & ~(size_t)127; return q; };
    float* e1 = (float*)A((size_t)N_NODES * 64 * 4);
    float* e2 = (float*)A((size_t)N_NODES * 32 * 4);
    float* e3 = (float*)A((size_t)N_NODES * 16 * 4);
    float* n0 = (float*)A((size_t)N_NODES * 4);
    float* n1 = (float*)A((size_t)N_NODES * 4);
    float* n2 = (float*)A((size_t)N_NODES * 4);
    float* cval = (float*)A((size_t)NE * 4);
    unsigned short* t0 = (unsigned short*)A((size_t)N_NODES * 64 * 2);
    unsigned short* t1 = (unsigned short*)A((size_t)N_NODES * 64 * 2);
    unsigned short* t2 = (unsigned short*)A((size_t)N_NODES * 32 * 2);
    int* ccol  = (int*)A((size_t)NE * 4);
    int* rs0   = (int*)A((size_t)(N_NODES + 1) * 4);
    int* rscur = (int*)A((size_t)N_NODES * 4);
    int* blk   = (int*)A(4096);
    size_t fixed = off;

    // ---- runtime chunk selection for the permute buffer ----
    int shift = -1, nch = 0;
    long cap = 0;
    for (int s = 18; s >= 15; --s) {
        long R = 1L << s;
        int nc = (int)((N_NODES + R - 1) / R);
        long c = (long)((double)NE * R / N_NODES) + 50000;
        if (c > NE) c = NE;
        size_t need = fixed + 3UL * NE * 4              // eslot, ccolc, cdst
                    + 2UL * nc * N_NODES * 4            // hist, kcur
                    + (size_t)c * 128 + 1024;           // buf
        if (need <= ws_size) { shift = s; nch = nc; cap = c; break; }
    }
    int* eslot = nullptr; int* ccolc = nullptr; int* cdst = nullptr;
    int* hist = nullptr;  int* kcur = nullptr;
    unsigned short* buf = nullptr;
    if (shift > 0) {
        eslot = (int*)A((size_t)NE * 4);
        ccolc = (int*)A((size_t)NE * 4);
        cdst  = (int*)A((size_t)NE * 4);
        hist  = (int*)A((size_t)nch * N_NODES * 4);
        kcur  = (int*)A((size_t)nch * N_NODES * 4);
        buf   = (unsigned short*)A((size_t)cap * 128);
    }

    // ---- CSR build ----
    hipMemsetAsync(rscur, 0, N_NODES * sizeof(int), stream);
    hist_csr<<<(NE + 255) / 256, 256, 0, stream>>>(rows, rscur);
    scan1<<<NB, 256, 0, stream>>>(rscur, rs0, blk);
    scan2<<<1, 1024, 0, stream>>>(blk);
    scan3_csr<<<NB, 256, 0, stream>>>(rs0, rscur, blk);
    csr_fill<<<(NE + 255) / 256, 256, 0, stream>>>(rows, cols, vals, rscur,
                                                   ccol, cval, eslot);
    build_t0<<<(N_NODES * 64 / 4 + 255) / 256, 256, 0, stream>>>(ue, ee, t0);

    if (shift > 0) {
        // ---- chunk-major CSC build (once, reused by L0+L1) ----
        hipMemsetAsync(hist, 0, (size_t)nch * N_NODES * sizeof(int), stream);
        khist<<<(NE + 255) / 256, 256, 0, stream>>>(rows, cols, hist, shift);
        for (int c = 0; c < nch; c++) {
            scan1<<<NB, 256, 0, stream>>>(hist + (size_t)c * N_NODES,
                                          kcur + (size_t)c * N_NODES, blk);
            scan2<<<1, 1024, 0, stream>>>(blk);
            kscan3base<<<NB, 256, 0, stream>>>(kcur + (size_t)c * N_NODES, blk,
                                               rs0, c << shift);
        }
        kfill<<<(NE + 255) / 256, 256, 0, stream>>>(rows, cols, kcur, ccolc,
                                                    cdst, eslot, shift);

        const int gridA = (int)(((size_t)cap * 32 + 255) / 256);
        // ---- layer 0 (permute path) ----
        for (int c = 0; c < nch; c++) {
            int lo = c << shift;
            int hi = lo + (1 << shift); if (hi > N_NODES) hi = N_NODES;
            int gridB = ((hi - lo) * 64 + 1023) / 1024;
            permuteA<<<gridA, 256, 0, stream>>>(ccolc, cdst, t0, buf, rs0, lo, hi);
            permB<64, 1, 1><<<gridB, 1024, 0, stream>>>(
                rs0, cval, buf, ue, ee, nullptr,
                Wg0, bg0, Wb0, bb0, e1, t1, n0, lo, hi);
        }
        // ---- layer 1 (permute path) ----
        for (int c = 0; c < nch; c++) {
            int lo = c << shift;
            int hi = lo + (1 << shift); if (hi > N_NODES) hi = N_NODES;
            int gridB = ((hi - lo) * 64 + 1023) / 1024;
            permuteA<<<gridA, 256, 0, stream>>>(ccolc, cdst, t1, buf, rs0, lo, hi);
            permB<32, 0, 1><<<gridB, 1024, 0, stream>>>(
                rs0, cval, buf, ue, ee, e1,
                Wg1, bg1, Wb1, bb1, e2, t2, n1, lo, hi);
        }
    } else {
        // ---- fallback: r7 gather path for L0/L1 ----
        gatherT<64, 64, 1, 1><<<12500, 1024, 0, stream>>>(
            rs0, ccol, cval, t0, ue, ee, nullptr,
            Wg0, bg0, Wb0, bb0, e1, t1, n0);
        gatherT<64, 32, 0, 1><<<12500, 1024, 0, stream>>>(
            rs0, ccol, cval, t1, ue, ee, e1,
            Wg1, bg1, Wb1, bb1, e2, t2, n1);
    }

    // ---- layer 2 (gather path — small) ----
    gatherT<32, 16, 0, 0><<<12500, 1024, 0, stream>>>(
        rs0, ccol, cval, t2, ue, ee, e2,
        Wg2, bg2, Wb2, bb2, e3, nullptr, n2);

    // ---- scoring ----
    score_kernel<<<(BATCH * 64) / 256, 256, 0, stream>>>(users, pos, neg, ue, ee,
                                                         e1, n0, e2, n1, e3, n2,
                                                         (float*)d_out);
}